// Round 5
// baseline (833.673 us; speedup 1.0000x reference)
//
#include <hip/hip_runtime.h>
#include <hip/hip_bf16.h>
#include <math.h>

// SlotAttention: B=64 N=4096 F=256 D=256 KVQ=256 H=4 S=8 DH=64 ITERS=3
// Round 5: LN pre-applied into bf16 Xh (chunked, mem-bound pre-pass); GEMM
// stages BOTH operands via global_load_lds (zero staging VALU, m97 2-phase);
// k_att with K/V fragment prefetch (T14) and finer grid; gruq 32 partials.

using frag_ab = __attribute__((ext_vector_type(8))) short;   // 8 bf16
using f32x4  = __attribute__((ext_vector_type(4))) float;

__device__ __forceinline__ unsigned short f2bf(float f) {
  unsigned int x = __float_as_uint(f);
  x += 0x7fffu + ((x >> 16) & 1u);   // RNE
  return (unsigned short)(x >> 16);
}
__device__ __forceinline__ float bf2f(unsigned short u) {
  return __uint_as_float((unsigned int)u << 16);
}

// ---------------------------------------------------------------------------
// Pre-pass: Xh[row][k] = bf16(LN(x[row])) for a 65536-row chunk. 1 wave/row.
__global__ __launch_bounds__(256) void k_precvt(
    const float* __restrict__ xsrc, const float* __restrict__ lnw,
    const float* __restrict__ lnb, unsigned short* __restrict__ Xh) {
  const int lane = threadIdx.x & 63;
  const long row = (long)blockIdx.x * 4 + (threadIdx.x >> 6);
  const float4 v = *(const float4*)(xsrc + row * 256 + lane * 4);
  float s = v.x + v.y + v.z + v.w;
  float ss = v.x * v.x + v.y * v.y + v.z * v.z + v.w * v.w;
#pragma unroll
  for (int m = 1; m < 64; m <<= 1) {
    s += __shfl_xor(s, m);
    ss += __shfl_xor(ss, m);
  }
  const float mean = s * (1.f / 256.f);
  const float rstd = rsqrtf(ss * (1.f / 256.f) - mean * mean + 1e-5f);
  const float4 w4 = *(const float4*)(lnw + lane * 4);
  const float4 b4 = *(const float4*)(lnb + lane * 4);
  const float x0 = (v.x - mean) * rstd * w4.x + b4.x;
  const float x1 = (v.y - mean) * rstd * w4.y + b4.y;
  const float x2 = (v.z - mean) * rstd * w4.z + b4.z;
  const float x3 = (v.w - mean) * rstd * w4.w + b4.w;
  uint2 o;
  o.x = (unsigned)f2bf(x0) | ((unsigned)f2bf(x1) << 16);
  o.y = (unsigned)f2bf(x2) | ((unsigned)f2bf(x3) << 16);
  *(uint2*)(Xh + row * 256 + lane * 4) = o;
}

// ---------------------------------------------------------------------------
// Weight cvt: Wb[n][k] = bf16(W[n][k]); n<256 -> wk, else wv.
__global__ __launch_bounds__(256) void k_wcvt(const float* __restrict__ wk,
                                              const float* __restrict__ wv,
                                              unsigned short* __restrict__ Wb) {
  const int lane = threadIdx.x & 63;
  const int n = blockIdx.x * 4 + (threadIdx.x >> 6);
  const float* W = (n < 256) ? (wk + n * 256) : (wv + (long)(n - 256) * 256);
  const float4 w4 = *(const float4*)(W + lane * 4);
  uint2 o;
  o.x = (unsigned)f2bf(w4.x) | ((unsigned)f2bf(w4.y) << 16);
  o.y = (unsigned)f2bf(w4.z) | ((unsigned)f2bf(w4.w) << 16);
  *(uint2*)(Wb + n * 256 + lane * 4) = o;
}

// ---------------------------------------------------------------------------
__global__ void k_transpose(const float* __restrict__ wih,
                            const float* __restrict__ whh,
                            const float* __restrict__ wqs,
                            float* __restrict__ wihT, float* __restrict__ whhT,
                            float* __restrict__ wqT) {
  const int idx = blockIdx.x * 256 + threadIdx.x;
  if (idx < 768 * 256) {
    const int g = idx >> 8, k = idx & 255;
    wihT[k * 768 + g] = wih[idx];
  } else if (idx < 2 * 768 * 256) {
    const int j = idx - 768 * 256;
    const int g = j >> 8, k = j & 255;
    whhT[k * 768 + g] = whh[j];
  } else {
    const int j = idx - 2 * 768 * 256;
    const int c = j >> 8, k = j & 255;
    wqT[k * 256 + c] = wqs[j];
  }
}

// ---------------------------------------------------------------------------
// Projection GEMM (per 65536-row chunk): BM=128 BN=128 BK=64, 4 waves (2x2),
// both operands via global_load_lds (linear LDS). Epilogue: K rows -> Kb,
// V transposed -> Vt[b][d][j].
__global__ __launch_bounds__(256) void k_gemm(
    const unsigned short* __restrict__ Xh, const unsigned short* __restrict__ Wb,
    unsigned short* __restrict__ Kb, unsigned short* __restrict__ Vt,
    long rowbase) {
  __shared__ __align__(16) char sh[32768];   // As 16K | Bs 16K; reused for repack
  unsigned short* As = (unsigned short*)sh;
  unsigned short* Bs = (unsigned short*)(sh + 16384);
  const int t = threadIdx.x;
  const int id = blockIdx.x;
  const int work = (id & 7) * 256 + (id >> 3);   // bijective XCD chunking (2048)
  const int mblk = work >> 2, nblk = work & 3;   // nblk fastest -> A L2 reuse
  const long row0 = (long)mblk * 128;            // within chunk
  const int n0 = nblk * 128;
  const int lane = t & 63, w = t >> 6;
  const int wm = w >> 1, wn = w & 1;
  const int li = lane & 15, kg = lane >> 4;

  f32x4 acc[4][4];
#pragma unroll
  for (int m = 0; m < 4; ++m)
#pragma unroll
    for (int n = 0; n < 4; ++n) acc[m][n] = (f32x4){0.f, 0.f, 0.f, 0.f};

  for (int ks = 0; ks < 4; ++ks) {
    if (ks) __syncthreads();
#pragma unroll
    for (int rnd = 0; rnd < 4; ++rnd) {
      const int o = rnd * 4096 + t * 16;
      const int r = o >> 7, kb = o & 127;
      __builtin_amdgcn_global_load_lds(
          (const unsigned int*)((const char*)Xh + (row0 + r) * 512 + ks * 128 + kb),
          (unsigned int*)((char*)As + o), 16, 0, 0);
      __builtin_amdgcn_global_load_lds(
          (const unsigned int*)((const char*)Wb + (long)(n0 + r) * 512 + ks * 128 + kb),
          (unsigned int*)((char*)Bs + o), 16, 0, 0);
    }
    __syncthreads();
#pragma unroll
    for (int kk = 0; kk < 2; ++kk) {
      frag_ab af[4], bf[4];
#pragma unroll
      for (int m = 0; m < 4; ++m)
        af[m] = *(const frag_ab*)((const char*)As +
                                  (wm * 64 + m * 16 + li) * 128 + kk * 64 + kg * 16);
#pragma unroll
      for (int n = 0; n < 4; ++n)
        bf[n] = *(const frag_ab*)((const char*)Bs +
                                  (wn * 64 + n * 16 + li) * 128 + kk * 64 + kg * 16);
#pragma unroll
      for (int m = 0; m < 4; ++m)
#pragma unroll
        for (int n = 0; n < 4; ++n)
          acc[m][n] =
              __builtin_amdgcn_mfma_f32_16x16x32_bf16(af[m], bf[n], acc[m][n], 0, 0, 0);
    }
  }
  __syncthreads();   // frag ds_reads drained before LDS reuse

  if (nblk < 2) {
    // K half: repack [128 r][128 c] bf16 (row-quarter XOR), coalesced store
    unsigned short* Krep = (unsigned short*)sh;
#pragma unroll
    for (int m = 0; m < 4; ++m)
#pragma unroll
      for (int n = 0; n < 4; ++n) {
        const int C = wn * 64 + n * 16 + li;
#pragma unroll
        for (int r = 0; r < 4; ++r) {
          const int R = wm * 64 + m * 16 + kg * 4 + r;
          const int off = (R * 256 + C * 2) ^ (((R >> 2) & 3) << 5);
          *(unsigned short*)((char*)Krep + off) = f2bf(acc[m][n][r]);
        }
      }
    __syncthreads();
#pragma unroll
    for (int p = 0; p < 8; ++p) {
      const int idx = p * 256 + t;
      const int R = idx >> 4, c = (idx & 15) * 16;
      const uint4 v =
          *(const uint4*)((char*)Krep + ((R * 256 + c) ^ (((R >> 2) & 3) << 5)));
      *(uint4*)(Kb + (rowbase + row0 + R) * 256 + nblk * 128 + c / 2) = v;
    }
  } else {
    // V half: transpose-repack [128 d][128 j] bf16 (d XOR swizzle), store Vt
    unsigned short* Vrep = (unsigned short*)sh;
#pragma unroll
    for (int m = 0; m < 4; ++m)
#pragma unroll
      for (int n = 0; n < 4; ++n) {
        const int dl = wn * 64 + n * 16 + li;
#pragma unroll
        for (int r = 0; r < 4; ++r) {
          const int R = wm * 64 + m * 16 + kg * 4 + r;   // j within tile
          const int off = dl * 256 + ((R * 2) ^ ((dl & 7) << 4));
          *(unsigned short*)((char*)Vrep + off) = f2bf(acc[m][n][r]);
        }
      }
    __syncthreads();
    const long grow0 = rowbase + row0;
    const long b = grow0 >> 12;
    const long jb = grow0 & 4095;
#pragma unroll
    for (int p = 0; p < 8; ++p) {
      const int idx = p * 256 + t;
      const int dl = idx >> 4, c16 = idx & 15;
      const uint4 v = *(const uint4*)((char*)Vrep + dl * 256 +
                                      ((c16 * 16) ^ ((dl & 7) << 4)));
      const int dglob = (nblk - 2) * 128 + dl;
      *(uint4*)(Vt + ((long)(b * 256 + dglob)) * 4096 + jb + c16 * 8) = v;
    }
  }
}

// ---------------------------------------------------------------------------
// LN(slots) + q = sn @ wq^T. One block per b (initial q only).
__global__ __launch_bounds__(256) void k_q(
    const float* __restrict__ slots, const float* __restrict__ lnw,
    const float* __restrict__ lnb, const float* __restrict__ wqT,
    float* __restrict__ qout) {
  __shared__ float sl[8 * 256];
  __shared__ float mstat[8], rstat[8];
  const int b = blockIdx.x, t = threadIdx.x;
#pragma unroll
  for (int i = 0; i < 8; ++i) sl[i * 256 + t] = slots[b * 2048 + i * 256 + t];
  __syncthreads();
  if (t < 8) {
    float s = 0.f, ss = 0.f;
    for (int k = 0; k < 256; ++k) {
      const float x = sl[t * 256 + k];
      s += x;
      ss += x * x;
    }
    const float m = s * (1.f / 256.f);
    mstat[t] = m;
    rstat[t] = rsqrtf(ss * (1.f / 256.f) - m * m + 1e-5f);
  }
  __syncthreads();
  const float w = lnw[t], bb = lnb[t];
#pragma unroll
  for (int i = 0; i < 8; ++i)
    sl[i * 256 + t] = (sl[i * 256 + t] - mstat[i]) * rstat[i] * w + bb;
  __syncthreads();
  float acc[8] = {};
  for (int k = 0; k < 256; k += 4) {
    const float w0 = wqT[(k + 0) * 256 + t];
    const float w1 = wqT[(k + 1) * 256 + t];
    const float w2 = wqT[(k + 2) * 256 + t];
    const float w3 = wqT[(k + 3) * 256 + t];
#pragma unroll
    for (int i = 0; i < 8; ++i) {
      const float4 x4 = *(const float4*)(sl + i * 256 + k);
      acc[i] += x4.x * w0 + x4.y * w1 + x4.z * w2 + x4.w * w3;
    }
  }
#pragma unroll
  for (int i = 0; i < 8; ++i) qout[b * 2048 + i * 256 + t] = acc[i];
}

// ---------------------------------------------------------------------------
// MFMA attention: block (jt,b) does 128 j in 4 chunks of 32. Wave = head.
// K/V fragments prefetched one chunk ahead (issue-early / use-late, T14).
template <bool LAST, bool FIRST>
__global__ __launch_bounds__(256) void k_att(
    const float* __restrict__ qin, const unsigned short* __restrict__ Kb,
    const unsigned short* __restrict__ Vt, float* __restrict__ upart,
    float* __restrict__ svpart, float* __restrict__ rowsum_part,
    float* __restrict__ attn_out) {
  __shared__ float dsm[32 * 33];
  __shared__ float wred[4 * 32];
  const int t = threadIdx.x;
  const int lane = t & 63;
  const int h = t >> 6;
  const int jt = blockIdx.x;     // 0..31
  const int b = blockIdx.y;      // 0..63
  const long j0 = (long)jt * 128;
  const int li = lane & 15;
  const int kg = lane >> 4;
  const bool ival = li < 8;

  frag_ab qf[2];
#pragma unroll
  for (int ksub = 0; ksub < 2; ++ksub) {
    union { frag_ab f; unsigned short u[8]; } tq;
#pragma unroll
    for (int e = 0; e < 8; ++e)
      tq.u[e] = ival ? f2bf(qin[b * 2048 + li * 256 + h * 64 + ksub * 32 + kg * 8 + e])
                     : (unsigned short)0;
    qf[ksub] = tq.f;
  }

  // per-chunk fragment bases
  const unsigned short* Kbase =
      Kb + ((long)b * 4096 + j0) * 256 + h * 64 + kg * 8;
  const unsigned short* Vbase =
      Vt + ((long)b * 256 + h * 64 + li) * 4096 + j0 + kg * 8;

  const int sc = t >> 3, sp = t & 7;
  float rs0 = 0, rs1 = 0, rs2 = 0, rs3 = 0;
  f32x4 pv[4];
#pragma unroll
  for (int d = 0; d < 4; ++d) pv[d] = (f32x4){0.f, 0.f, 0.f, 0.f};
  float sv[4] = {0.f, 0.f, 0.f, 0.f};

  frag_ab afc[2][2], afn[2][2], vfc[4], vfn[4];
#pragma unroll
  for (int jsub = 0; jsub < 2; ++jsub)
#pragma unroll
    for (int ksub = 0; ksub < 2; ++ksub)
      afc[jsub][ksub] =
          *(const frag_ab*)(Kbase + (long)(jsub * 16 + li) * 256 + ksub * 32);
#pragma unroll
  for (int dt = 0; dt < 4; ++dt)
    vfc[dt] = *(const frag_ab*)(Vbase + (long)dt * 16 * 4096);

#pragma unroll
  for (int ch = 0; ch < 4; ++ch) {
    const long jc = j0 + ch * 32;
    // QK^T with current K frags
    f32x4 dacc[2];
    dacc[0] = (f32x4){0.f, 0.f, 0.f, 0.f};
    dacc[1] = (f32x4){0.f, 0.f, 0.f, 0.f};
#pragma unroll
    for (int jsub = 0; jsub < 2; ++jsub)
#pragma unroll
      for (int ksub = 0; ksub < 2; ++ksub)
        dacc[jsub] = __builtin_amdgcn_mfma_f32_16x16x32_bf16(
            afc[jsub][ksub], qf[ksub], dacc[jsub], 0, 0, 0);
    // prefetch next chunk's K frags (latency hidden under softmax phase)
    if (ch < 3) {
#pragma unroll
      for (int jsub = 0; jsub < 2; ++jsub)
#pragma unroll
        for (int ksub = 0; ksub < 2; ++ksub)
          afn[jsub][ksub] = *(const frag_ab*)(Kbase + (ch + 1) * 32 * 256 +
                                              (long)(jsub * 16 + li) * 256 +
                                              ksub * 32);
    }
    __syncthreads();
    if (ival) {
#pragma unroll
      for (int jsub = 0; jsub < 2; ++jsub)
#pragma unroll
        for (int r = 0; r < 4; ++r)
          dsm[(jsub * 16 + kg * 4 + r) * 33 + li * 4 + h] = dacc[jsub][r] * 0.125f;
    }
    __syncthreads();
    {
      float v0 = dsm[sc * 33 + sp * 4 + 0];
      float v1 = dsm[sc * 33 + sp * 4 + 1];
      float v2 = dsm[sc * 33 + sp * 4 + 2];
      float v3 = dsm[sc * 33 + sp * 4 + 3];
      float mx = fmaxf(fmaxf(v0, v1), fmaxf(v2, v3));
      mx = fmaxf(mx, __shfl_xor(mx, 1));
      mx = fmaxf(mx, __shfl_xor(mx, 2));
      mx = fmaxf(mx, __shfl_xor(mx, 4));
      v0 = __expf(v0 - mx); v1 = __expf(v1 - mx);
      v2 = __expf(v2 - mx); v3 = __expf(v3 - mx);
      float sum = v0 + v1 + v2 + v3;
      sum += __shfl_xor(sum, 1);
      sum += __shfl_xor(sum, 2);
      sum += __shfl_xor(sum, 4);
      const float inv = 1.f / sum;
      v0 *= inv; v1 *= inv; v2 *= inv; v3 *= inv;
      dsm[sc * 33 + sp * 4 + 0] = v0;
      dsm[sc * 33 + sp * 4 + 1] = v1;
      dsm[sc * 33 + sp * 4 + 2] = v2;
      dsm[sc * 33 + sp * 4 + 3] = v3;
      rs0 += v0; rs1 += v1; rs2 += v2; rs3 += v3;
      if (LAST)
        attn_out[((long)(b * 8 + sp)) * 4096 + jc + sc] =
            (v0 + v1 + v2 + v3) * 0.25f;
    }
    __syncthreads();
    // prefetch next chunk's V frags; then PV with current
    if (ch < 3) {
#pragma unroll
      for (int dt = 0; dt < 4; ++dt)
        vfn[dt] = *(const frag_ab*)(Vbase + (ch + 1) * 32 + (long)dt * 16 * 4096);
    }
    frag_ab pa;
    {
      union { frag_ab f; unsigned short u[8]; } tp;
#pragma unroll
      for (int e = 0; e < 8; ++e)
        tp.u[e] = ival ? f2bf(dsm[(kg * 8 + e) * 33 + li * 4 + h]) : (unsigned short)0;
      pa = tp.f;
    }
#pragma unroll
    for (int dt = 0; dt < 4; ++dt) {
      pv[dt] = __builtin_amdgcn_mfma_f32_16x16x32_bf16(pa, vfc[dt], pv[dt], 0, 0, 0);
      if (FIRST) {
        const unsigned short* vu = (const unsigned short*)&vfc[dt];
        float svl = 0.f;
#pragma unroll
        for (int e = 0; e < 8; ++e) svl += bf2f(vu[e]);
        sv[dt] += svl;
      }
    }
    if (ch < 3) {
#pragma unroll
      for (int jsub = 0; jsub < 2; ++jsub)
#pragma unroll
        for (int ksub = 0; ksub < 2; ++ksub) afc[jsub][ksub] = afn[jsub][ksub];
#pragma unroll
      for (int dt = 0; dt < 4; ++dt) vfc[dt] = vfn[dt];
    }
  }
  if (kg < 2) {
#pragma unroll
    for (int dt = 0; dt < 4; ++dt)
#pragma unroll
      for (int r = 0; r < 4; ++r)
        upart[(((long)(jt * 64 + b)) * 8 + kg * 4 + r) * 256 + h * 64 + dt * 16 + li] =
            pv[dt][r];
  }
  if (FIRST) {
#pragma unroll
    for (int dt = 0; dt < 4; ++dt) {
      sv[dt] += __shfl_xor(sv[dt], 16);
      sv[dt] += __shfl_xor(sv[dt], 32);
    }
    if (kg == 0) {
#pragma unroll
      for (int dt = 0; dt < 4; ++dt)
        svpart[((long)(jt * 64 + b)) * 256 + h * 64 + dt * 16 + li] = sv[dt];
    }
  }
  rs0 += __shfl_xor(rs0, 8); rs0 += __shfl_xor(rs0, 16); rs0 += __shfl_xor(rs0, 32);
  rs1 += __shfl_xor(rs1, 8); rs1 += __shfl_xor(rs1, 16); rs1 += __shfl_xor(rs1, 32);
  rs2 += __shfl_xor(rs2, 8); rs2 += __shfl_xor(rs2, 16); rs2 += __shfl_xor(rs2, 32);
  rs3 += __shfl_xor(rs3, 8); rs3 += __shfl_xor(rs3, 16); rs3 += __shfl_xor(rs3, 32);
  if ((t & 63) < 8) {
    float* wr = wred + (t >> 6) * 32 + sp * 4;
    wr[0] = rs0; wr[1] = rs1; wr[2] = rs2; wr[3] = rs3;
  }
  __syncthreads();
  if (t < 32)
    rowsum_part[((long)(jt * 64 + b)) * 32 + t] =
        wred[t] + wred[32 + t] + wred[64 + t] + wred[96 + t];
}

// ---------------------------------------------------------------------------
// GRU cell fused with next-iteration LN + q projection. One block per b.
template <bool LAST>
__global__ __launch_bounds__(256) void k_gruq(
    const float* __restrict__ upart, const float* __restrict__ svpart,
    const float* __restrict__ rowsum_part, const float* __restrict__ wihT,
    const float* __restrict__ whhT, const float* __restrict__ bih,
    const float* __restrict__ bhh, const float* __restrict__ lnw,
    const float* __restrict__ lnb, const float* __restrict__ wqT,
    float* __restrict__ slots, float* __restrict__ qout,
    float* __restrict__ dout) {
  __shared__ float xl[8 * 256];
  __shared__ float hl[8 * 256];
  __shared__ float rs[32];
  __shared__ float mstat[8], rstat[8];
  const int t = threadIdx.x;
  const int b = blockIdx.x;
  if (t < 32) {
    float s2 = 0.f;
#pragma unroll
    for (int p = 0; p < 32; ++p) s2 += rowsum_part[((long)(p * 64 + b)) * 32 + t];
    rs[t] = 1.f / (s2 + 4096.f * 1e-8f);
  }
  float svs = 0.f;
#pragma unroll
  for (int p = 0; p < 32; ++p) svs += svpart[((long)(p * 64 + b)) * 256 + t];
  __syncthreads();
  const int hcol = t >> 6;
#pragma unroll
  for (int r = 0; r < 8; ++r) {
    float pp = 0.f;
#pragma unroll
    for (int p = 0; p < 32; ++p)
      pp += upart[(((long)(p * 64 + b)) * 8 + r) * 256 + t];
    xl[r * 256 + t] = (pp + 1e-8f * svs) * rs[r * 4 + hcol];
    hl[r * 256 + t] = slots[b * 2048 + r * 256 + t];
  }
  __syncthreads();
  float air[8] = {}, aiz[8] = {}, ain[8] = {};
  float ahr[8] = {}, ahz[8] = {}, ahn[8] = {};
  for (int k = 0; k < 256; k += 4) {
    float wir[4], wiz[4], win_[4], whr[4], whz[4], whn[4];
#pragma unroll
    for (int u = 0; u < 4; ++u) {
      wir[u] = wihT[(k + u) * 768 + t];
      wiz[u] = wihT[(k + u) * 768 + 256 + t];
      win_[u] = wihT[(k + u) * 768 + 512 + t];
      whr[u] = whhT[(k + u) * 768 + t];
      whz[u] = whhT[(k + u) * 768 + 256 + t];
      whn[u] = whhT[(k + u) * 768 + 512 + t];
    }
#pragma unroll
    for (int r = 0; r < 8; ++r) {
      const float4 x4 = *(const float4*)(xl + r * 256 + k);
      const float4 h4 = *(const float4*)(hl + r * 256 + k);
      air[r] += x4.x * wir[0] + x4.y * wir[1] + x4.z * wir[2] + x4.w * wir[3];
      aiz[r] += x4.x * wiz[0] + x4.y * wiz[1] + x4.z * wiz[2] + x4.w * wiz[3];
      ain[r] += x4.x * win_[0] + x4.y * win_[1] + x4.z * win_[2] + x4.w * win_[3];
      ahr[r] += h4.x * whr[0] + h4.y * whr[1] + h4.z * whr[2] + h4.w * whr[3];
      ahz[r] += h4.x * whz[0] + h4.y * whz[1] + h4.z * whz[2] + h4.w * whz[3];
      ahn[r] += h4.x * whn[0] + h4.y * whn[1] + h4.z * whn[2] + h4.w * whn[3];
    }
  }
  const float bir = bih[t], biz = bih[256 + t], bin_ = bih[512 + t];
  const float bhr = bhh[t], bhz = bhh[256 + t], bhn = bhh[512 + t];
  float hn[8];
#pragma unroll
  for (int r = 0; r < 8; ++r) {
    const float rr = 1.f / (1.f + __expf(-(air[r] + bir + ahr[r] + bhr)));
    const float zz = 1.f / (1.f + __expf(-(aiz[r] + biz + ahz[r] + bhz)));
    const float nn2 = tanhf(ain[r] + bin_ + rr * (ahn[r] + bhn));
    hn[r] = (1.f - zz) * nn2 + zz * hl[r * 256 + t];
    slots[b * 2048 + r * 256 + t] = hn[r];
    if (LAST) dout[b * 2048 + r * 256 + t] = hn[r];
  }
  if (LAST) return;
  // ---- fused LN + q for the next iteration ----
  __syncthreads();
#pragma unroll
  for (int r = 0; r < 8; ++r) xl[r * 256 + t] = hn[r];
  __syncthreads();
  if (t < 8) {
    float s = 0.f, ss = 0.f;
    for (int k = 0; k < 256; ++k) {
      const float x = xl[t * 256 + k];
      s += x;
      ss += x * x;
    }
    const float m = s * (1.f / 256.f);
    mstat[t] = m;
    rstat[t] = rsqrtf(ss * (1.f / 256.f) - m * m + 1e-5f);
  }
  __syncthreads();
  const float w = lnw[t], bb = lnb[t];
#pragma unroll
  for (int i = 0; i < 8; ++i)
    xl[i * 256 + t] = (xl[i * 256 + t] - mstat[i]) * rstat[i] * w + bb;
  __syncthreads();
  float acq[8] = {};
  for (int k = 0; k < 256; k += 4) {
    const float w0 = wqT[(k + 0) * 256 + t];
    const float w1 = wqT[(k + 1) * 256 + t];
    const float w2 = wqT[(k + 2) * 256 + t];
    const float w3 = wqT[(k + 3) * 256 + t];
#pragma unroll
    for (int i = 0; i < 8; ++i) {
      const float4 x4 = *(const float4*)(xl + i * 256 + k);
      acq[i] += x4.x * w0 + x4.y * w1 + x4.z * w2 + x4.w * w3;
    }
  }
#pragma unroll
  for (int i = 0; i < 8; ++i) qout[b * 2048 + i * 256 + t] = acq[i];
}

// ---------------------------------------------------------------------------
extern "C" void kernel_launch(void* const* d_in, const int* in_sizes, int n_in,
                              void* d_out, int out_size, void* d_ws,
                              size_t ws_size, hipStream_t stream) {
  const float* xin = (const float*)d_in[0];
  const float* cond = (const float*)d_in[1];
  const float* lnin_w = (const float*)d_in[2];
  const float* lnin_b = (const float*)d_in[3];
  const float* lns_w = (const float*)d_in[4];
  const float* lns_b = (const float*)d_in[5];
  const float* wq = (const float*)d_in[6];
  const float* wk = (const float*)d_in[7];
  const float* wv = (const float*)d_in[8];
  const float* gwih = (const float*)d_in[9];
  const float* gwhh = (const float*)d_in[10];
  const float* gbih = (const float*)d_in[11];
  const float* gbhh = (const float*)d_in[12];
  float* out = (float*)d_out;

  char* ws = (char*)d_ws;
  unsigned short* Kb = (unsigned short*)ws;  ws += 64l * 4096 * 256 * 2;   // 128MB
  unsigned short* Vt = (unsigned short*)ws;  ws += 64l * 256 * 4096 * 2;   // 128MB
  char* REG = ws;                            ws += 65536l * 256 * 2;       // 32MB
  // REG region: Xh (projection phase) then upart/svpart/rowsum/qbuf (iters)
  unsigned short* Xh = (unsigned short*)REG;
  float* upart = (float*)REG;                                  // 16MB
  float* svpart = (float*)(REG + 32l * 64 * 8 * 256 * 4);      // 2MB
  float* rowsum_part = (float*)(REG + 18l * 1024 * 1024);      // 256KB
  float* qbuf = (float*)(REG + 19l * 1024 * 1024);             // 512KB
  float* slots = (float*)ws;                 ws += 512l * 256 * 4;
  float* wihT = (float*)ws;                  ws += 256l * 768 * 4;
  float* whhT = (float*)ws;                  ws += 256l * 768 * 4;
  float* wqT = (float*)ws;                   ws += 256l * 256 * 4;
  unsigned short* Wb = (unsigned short*)ws;  ws += 512l * 256 * 2;
  // total ~291 MB

  hipMemcpyAsync(slots, cond, 512 * 256 * 4, hipMemcpyDeviceToDevice, stream);
  k_wcvt<<<128, 256, 0, stream>>>(wk, wv, Wb);
  k_transpose<<<1792, 256, 0, stream>>>(gwih, gwhh, wq, wihT, whhT, wqT);
  // projection in 4 row-chunks of 65536 (Xh reused)
  for (int c = 0; c < 4; ++c) {
    k_precvt<<<16384, 256, 0, stream>>>(xin + (long)c * 65536 * 256, lnin_w,
                                        lnin_b, Xh);
    k_gemm<<<2048, 256, 0, stream>>>(Xh, Wb, Kb, Vt, (long)c * 65536);
  }
  k_q<<<64, 256, 0, stream>>>(slots, lns_w, lns_b, wqT, qbuf);

  // iter 0
  k_att<false, true><<<dim3(32, 64), 256, 0, stream>>>(
      qbuf, Kb, Vt, upart, svpart, rowsum_part, out + 131072);
  k_gruq<false><<<64, 256, 0, stream>>>(upart, svpart, rowsum_part, wihT, whhT,
                                        gbih, gbhh, lns_w, lns_b, wqT, slots,
                                        qbuf, out);
  // iter 1
  k_att<false, false><<<dim3(32, 64), 256, 0, stream>>>(
      qbuf, Kb, Vt, upart, svpart, rowsum_part, out + 131072);
  k_gruq<false><<<64, 256, 0, stream>>>(upart, svpart, rowsum_part, wihT, whhT,
                                        gbih, gbhh, lns_w, lns_b, wqT, slots,
                                        qbuf, out);
  // iter 2
  k_att<true, false><<<dim3(32, 64), 256, 0, stream>>>(
      qbuf, Kb, Vt, upart, svpart, rowsum_part, out + 131072);
  k_gruq<true><<<64, 256, 0, stream>>>(upart, svpart, rowsum_part, wihT, whhT,
                                       gbih, gbhh, lns_w, lns_b, wqT, slots,
                                       qbuf, out);
}

// Round 6
// 731.302 us; speedup vs baseline: 1.1400x; 1.1400x over previous
//
#include <hip/hip_runtime.h>
#include <hip/hip_bf16.h>
#include <math.h>

// SlotAttention: B=64 N=4096 F=256 D=256 KVQ=256 H=4 S=8 DH=64 ITERS=3
// Round 6: single-pass Xh pre-pass + dbuf global_load_lds GEMM; barrier-free
// k_att (wave owns j-range, all heads via zero-padded Q, in-register inverted
// softmax, wave-local LDS P transpose); gruq 16 partials.

using frag_ab = __attribute__((ext_vector_type(8))) short;   // 8 bf16
using f32x4  = __attribute__((ext_vector_type(4))) float;

__device__ __forceinline__ unsigned short f2bf(float f) {
  unsigned int x = __float_as_uint(f);
  x += 0x7fffu + ((x >> 16) & 1u);   // RNE
  return (unsigned short)(x >> 16);
}
__device__ __forceinline__ float bf2f(unsigned short u) {
  return __uint_as_float((unsigned int)u << 16);
}

// ---------------------------------------------------------------------------
// Pre-pass: Xh[row][k] = bf16(LN(x[row])), all 262144 rows. 1 wave/row.
__global__ __launch_bounds__(256) void k_precvt(
    const float* __restrict__ xsrc, const float* __restrict__ lnw,
    const float* __restrict__ lnb, unsigned short* __restrict__ Xh) {
  const int lane = threadIdx.x & 63;
  const long row = (long)blockIdx.x * 4 + (threadIdx.x >> 6);
  const float4 v = *(const float4*)(xsrc + row * 256 + lane * 4);
  float s = v.x + v.y + v.z + v.w;
  float ss = v.x * v.x + v.y * v.y + v.z * v.z + v.w * v.w;
#pragma unroll
  for (int m = 1; m < 64; m <<= 1) {
    s += __shfl_xor(s, m);
    ss += __shfl_xor(ss, m);
  }
  const float mean = s * (1.f / 256.f);
  const float rstd = rsqrtf(ss * (1.f / 256.f) - mean * mean + 1e-5f);
  const float4 w4 = *(const float4*)(lnw + lane * 4);
  const float4 b4 = *(const float4*)(lnb + lane * 4);
  const float x0 = (v.x - mean) * rstd * w4.x + b4.x;
  const float x1 = (v.y - mean) * rstd * w4.y + b4.y;
  const float x2 = (v.z - mean) * rstd * w4.z + b4.z;
  const float x3 = (v.w - mean) * rstd * w4.w + b4.w;
  uint2 o;
  o.x = (unsigned)f2bf(x0) | ((unsigned)f2bf(x1) << 16);
  o.y = (unsigned)f2bf(x2) | ((unsigned)f2bf(x3) << 16);
  *(uint2*)(Xh + row * 256 + lane * 4) = o;
}

// ---------------------------------------------------------------------------
// Weight cvt: Wb[n][k] = bf16(W[n][k]); n<256 -> wk, else wv.
__global__ __launch_bounds__(256) void k_wcvt(const float* __restrict__ wk,
                                              const float* __restrict__ wv,
                                              unsigned short* __restrict__ Wb) {
  const int lane = threadIdx.x & 63;
  const int n = blockIdx.x * 4 + (threadIdx.x >> 6);
  const float* W = (n < 256) ? (wk + n * 256) : (wv + (long)(n - 256) * 256);
  const float4 w4 = *(const float4*)(W + lane * 4);
  uint2 o;
  o.x = (unsigned)f2bf(w4.x) | ((unsigned)f2bf(w4.y) << 16);
  o.y = (unsigned)f2bf(w4.z) | ((unsigned)f2bf(w4.w) << 16);
  *(uint2*)(Wb + n * 256 + lane * 4) = o;
}

// ---------------------------------------------------------------------------
__global__ void k_transpose(const float* __restrict__ wih,
                            const float* __restrict__ whh,
                            const float* __restrict__ wqs,
                            float* __restrict__ wihT, float* __restrict__ whhT,
                            float* __restrict__ wqT) {
  const int idx = blockIdx.x * 256 + threadIdx.x;
  if (idx < 768 * 256) {
    const int g = idx >> 8, k = idx & 255;
    wihT[k * 768 + g] = wih[idx];
  } else if (idx < 2 * 768 * 256) {
    const int j = idx - 768 * 256;
    const int g = j >> 8, k = j & 255;
    whhT[k * 768 + g] = whh[j];
  } else {
    const int j = idx - 2 * 768 * 256;
    const int c = j >> 8, k = j & 255;
    wqT[k * 256 + c] = wqs[j];
  }
}

// ---------------------------------------------------------------------------
// Projection GEMM: BM=128 BN=128 BK=64, double-buffered LDS, both operands
// via global_load_lds. Epilogue: K rows -> Kb, V transposed -> Vt[b][d][j].
__global__ __launch_bounds__(256) void k_gemm(
    const unsigned short* __restrict__ Xh, const unsigned short* __restrict__ Wb,
    unsigned short* __restrict__ Kb, unsigned short* __restrict__ Vt) {
  __shared__ __align__(16) char sh[65536];   // [2][As 16K | Bs 16K]
  const int t = threadIdx.x;
  const int id = blockIdx.x;
  const int work = (id & 7) * 1024 + (id >> 3);   // XCD chunking; nblk fastest
  const int mblk = work >> 2, nblk = work & 3;
  const long row0 = (long)mblk * 128;
  const int n0 = nblk * 128;
  const int lane = t & 63, w = t >> 6;
  const int wm = w >> 1, wn = w & 1;
  const int li = lane & 15, kg = lane >> 4;

  f32x4 acc[4][4];
#pragma unroll
  for (int m = 0; m < 4; ++m)
#pragma unroll
    for (int n = 0; n < 4; ++n) acc[m][n] = (f32x4){0.f, 0.f, 0.f, 0.f};

  auto stage = [&](int buf, int ks) {
    char* As = sh + (buf << 15);
    char* Bs = As + 16384;
#pragma unroll
    for (int rnd = 0; rnd < 4; ++rnd) {
      const int o = rnd * 4096 + t * 16;
      const int r = o >> 7, kb = o & 127;
      __builtin_amdgcn_global_load_lds(
          (const unsigned int*)((const char*)Xh + (row0 + r) * 512 + ks * 128 + kb),
          (unsigned int*)(As + o), 16, 0, 0);
      __builtin_amdgcn_global_load_lds(
          (const unsigned int*)((const char*)Wb + (long)(n0 + r) * 512 + ks * 128 + kb),
          (unsigned int*)(Bs + o), 16, 0, 0);
    }
  };

  stage(0, 0);
  __syncthreads();
  for (int ks = 0; ks < 4; ++ks) {
    const int cur = ks & 1;
    if (ks < 3) stage(cur ^ 1, ks + 1);   // overlaps MFMA below; drained at barrier
    const char* As = sh + (cur << 15);
    const char* Bs = As + 16384;
#pragma unroll
    for (int kk = 0; kk < 2; ++kk) {
      frag_ab af[4], bf[4];
#pragma unroll
      for (int m = 0; m < 4; ++m)
        af[m] = *(const frag_ab*)(As + (wm * 64 + m * 16 + li) * 128 + kk * 64 + kg * 16);
#pragma unroll
      for (int n = 0; n < 4; ++n)
        bf[n] = *(const frag_ab*)(Bs + (wn * 64 + n * 16 + li) * 128 + kk * 64 + kg * 16);
#pragma unroll
      for (int m = 0; m < 4; ++m)
#pragma unroll
        for (int n = 0; n < 4; ++n)
          acc[m][n] =
              __builtin_amdgcn_mfma_f32_16x16x32_bf16(af[m], bf[n], acc[m][n], 0, 0, 0);
    }
    __syncthreads();
  }

  if (nblk < 2) {
    // K half: repack [128 r][128 c] bf16 (row-quarter XOR), coalesced store
    unsigned short* Krep = (unsigned short*)sh;
#pragma unroll
    for (int m = 0; m < 4; ++m)
#pragma unroll
      for (int n = 0; n < 4; ++n) {
        const int C = wn * 64 + n * 16 + li;
#pragma unroll
        for (int r = 0; r < 4; ++r) {
          const int R = wm * 64 + m * 16 + kg * 4 + r;
          const int off = (R * 256 + C * 2) ^ (((R >> 2) & 3) << 5);
          *(unsigned short*)((char*)Krep + off) = f2bf(acc[m][n][r]);
        }
      }
    __syncthreads();
#pragma unroll
    for (int p = 0; p < 8; ++p) {
      const int idx = p * 256 + t;
      const int R = idx >> 4, c = (idx & 15) * 16;
      const uint4 v =
          *(const uint4*)((char*)Krep + ((R * 256 + c) ^ (((R >> 2) & 3) << 5)));
      *(uint4*)(Kb + (row0 + R) * 256 + nblk * 128 + c / 2) = v;
    }
  } else {
    // V half: transpose-repack [128 d][128 j] bf16 (d XOR swizzle), store Vt
    unsigned short* Vrep = (unsigned short*)sh;
#pragma unroll
    for (int m = 0; m < 4; ++m)
#pragma unroll
      for (int n = 0; n < 4; ++n) {
        const int dl = wn * 64 + n * 16 + li;
#pragma unroll
        for (int r = 0; r < 4; ++r) {
          const int R = wm * 64 + m * 16 + kg * 4 + r;   // j within tile
          const int off = dl * 256 + ((R * 2) ^ ((dl & 7) << 4));
          *(unsigned short*)((char*)Vrep + off) = f2bf(acc[m][n][r]);
        }
      }
    __syncthreads();
    const long b = row0 >> 12;
    const long jb = row0 & 4095;
#pragma unroll
    for (int p = 0; p < 8; ++p) {
      const int idx = p * 256 + t;
      const int dl = idx >> 4, c16 = idx & 15;
      const uint4 v = *(const uint4*)((char*)Vrep + dl * 256 +
                                      ((c16 * 16) ^ ((dl & 7) << 4)));
      const int dglob = (nblk - 2) * 128 + dl;
      *(uint4*)(Vt + ((long)(b * 256 + dglob)) * 4096 + jb + c16 * 8) = v;
    }
  }
}

// ---------------------------------------------------------------------------
// LN(slots) + q = sn @ wq^T. One block per b (initial q only).
__global__ __launch_bounds__(256) void k_q(
    const float* __restrict__ slots, const float* __restrict__ lnw,
    const float* __restrict__ lnb, const float* __restrict__ wqT,
    float* __restrict__ qout) {
  __shared__ float sl[8 * 256];
  __shared__ float mstat[8], rstat[8];
  const int b = blockIdx.x, t = threadIdx.x;
#pragma unroll
  for (int i = 0; i < 8; ++i) sl[i * 256 + t] = slots[b * 2048 + i * 256 + t];
  __syncthreads();
  if (t < 8) {
    float s = 0.f, ss = 0.f;
    for (int k = 0; k < 256; ++k) {
      const float x = sl[t * 256 + k];
      s += x;
      ss += x * x;
    }
    const float m = s * (1.f / 256.f);
    mstat[t] = m;
    rstat[t] = rsqrtf(ss * (1.f / 256.f) - m * m + 1e-5f);
  }
  __syncthreads();
  const float w = lnw[t], bb = lnb[t];
#pragma unroll
  for (int i = 0; i < 8; ++i)
    sl[i * 256 + t] = (sl[i * 256 + t] - mstat[i]) * rstat[i] * w + bb;
  __syncthreads();
  float acc[8] = {};
  for (int k = 0; k < 256; k += 4) {
    const float w0 = wqT[(k + 0) * 256 + t];
    const float w1 = wqT[(k + 1) * 256 + t];
    const float w2 = wqT[(k + 2) * 256 + t];
    const float w3 = wqT[(k + 3) * 256 + t];
#pragma unroll
    for (int i = 0; i < 8; ++i) {
      const float4 x4 = *(const float4*)(sl + i * 256 + k);
      acc[i] += x4.x * w0 + x4.y * w1 + x4.z * w2 + x4.w * w3;
    }
  }
#pragma unroll
  for (int i = 0; i < 8; ++i) qout[b * 2048 + i * 256 + t] = acc[i];
}

// ---------------------------------------------------------------------------
// Barrier-free attention: wave owns 64 j (2 chunks of 32), computes ALL heads
// via zero-padded Q (B cols = 32 (i,h), ih = i*4+h). QK D-layout (row=j,
// col=ih) -> inverted softmax is an in-register shfl reduction over li.
// P -> PV via wave-private LDS transpose (lgkmcnt only, no barriers).
template <bool LAST, bool FIRST>
__global__ __launch_bounds__(256) void k_att(
    const float* __restrict__ qin, const unsigned short* __restrict__ Kb,
    const unsigned short* __restrict__ Vt, float* __restrict__ upart,
    float* __restrict__ svpart, float* __restrict__ rowsum_part,
    float* __restrict__ attn_out) {
  __shared__ __align__(16) unsigned short Qs[32 * 256];  // 16KB zero-padded Q
  __shared__ __align__(16) unsigned short Ps[4][1024];   // per-wave P scratch
  __shared__ float ured[4][2048];
  __shared__ float wred[4][32];
  __shared__ float svred[4][256];
  const int t = threadIdx.x;
  const int lane = t & 63, wid = t >> 6;
  const int li = lane & 15, kg = lane >> 4;
  const int b = blockIdx.y;
  const long j0 = (long)blockIdx.x * 256 + wid * 64;

  // ---- stage zero-padded Q: Qs[ih][k] = (k>>6==h) ? bf16(q[i][k]) : 0 ----
  {
    const int ihq = t >> 3;
    const int iq = ihq >> 2, hq = ihq & 3;
    const int kb0 = (t & 7) * 32;
    const bool nz = (kb0 >> 6) == hq;
#pragma unroll
    for (int u = 0; u < 4; ++u) {
      const int k0 = kb0 + u * 8;
      uint4 g = make_uint4(0u, 0u, 0u, 0u);
      if (nz) {
        const float* qp = qin + b * 2048 + iq * 256 + k0;
        g.x = (unsigned)f2bf(qp[0]) | ((unsigned)f2bf(qp[1]) << 16);
        g.y = (unsigned)f2bf(qp[2]) | ((unsigned)f2bf(qp[3]) << 16);
        g.z = (unsigned)f2bf(qp[4]) | ((unsigned)f2bf(qp[5]) << 16);
        g.w = (unsigned)f2bf(qp[6]) | ((unsigned)f2bf(qp[7]) << 16);
      }
      *(uint4*)((char*)Qs + ihq * 512 + ((k0 * 2) ^ ((ihq & 7) << 4))) = g;
    }
  }
  __syncthreads();

  float rsum0 = 0.f, rsum1 = 0.f;
  f32x4 pv[4][4];
#pragma unroll
  for (int h = 0; h < 4; ++h)
#pragma unroll
    for (int dt = 0; dt < 4; ++dt) pv[h][dt] = (f32x4){0.f, 0.f, 0.f, 0.f};
  float svl[16];
#pragma unroll
  for (int u = 0; u < 16; ++u) svl[u] = 0.f;

  unsigned short* Pw = Ps[wid];

  for (int ch = 0; ch < 2; ++ch) {
    const long jc = j0 + ch * 32;
    // ---- QK^T: D[j][ih], K=256 with Q zero-padded per head ----
    f32x4 dacc[2][2];
    dacc[0][0] = (f32x4){0.f, 0.f, 0.f, 0.f};
    dacc[0][1] = (f32x4){0.f, 0.f, 0.f, 0.f};
    dacc[1][0] = (f32x4){0.f, 0.f, 0.f, 0.f};
    dacc[1][1] = (f32x4){0.f, 0.f, 0.f, 0.f};
#pragma unroll
    for (int jsub = 0; jsub < 2; ++jsub) {
      frag_ab kf[8];
      const unsigned short* kp =
          Kb + ((long)b * 4096 + jc + jsub * 16 + li) * 256 + kg * 8;
#pragma unroll
      for (int ks = 0; ks < 8; ++ks) kf[ks] = *(const frag_ab*)(kp + ks * 32);
#pragma unroll
      for (int g = 0; g < 2; ++g) {
        const int ihb = g * 16 + li;
        const char* qrow = (const char*)Qs + ihb * 512;
        const int swz = (ihb & 7) << 4;
#pragma unroll
        for (int ks = 0; ks < 8; ++ks) {
          const frag_ab qf = *(const frag_ab*)(qrow + ((ks * 64 + kg * 16) ^ swz));
          dacc[jsub][g] = __builtin_amdgcn_mfma_f32_16x16x32_bf16(
              kf[ks], qf, dacc[jsub][g], 0, 0, 0);
        }
      }
    }
    // ---- inverted softmax over 32 ih per j, fully in-register ----
    float p[2][2][4];
#pragma unroll
    for (int jsub = 0; jsub < 2; ++jsub) {
#pragma unroll
      for (int r = 0; r < 4; ++r) {
        const float d0 = dacc[jsub][0][r] * 0.125f;
        const float d1 = dacc[jsub][1][r] * 0.125f;
        float mx = fmaxf(d0, d1);
        mx = fmaxf(mx, __shfl_xor(mx, 1));
        mx = fmaxf(mx, __shfl_xor(mx, 2));
        mx = fmaxf(mx, __shfl_xor(mx, 4));
        mx = fmaxf(mx, __shfl_xor(mx, 8));
        float e0 = __expf(d0 - mx), e1 = __expf(d1 - mx);
        float sm = e0 + e1;
        sm += __shfl_xor(sm, 1);
        sm += __shfl_xor(sm, 2);
        sm += __shfl_xor(sm, 4);
        sm += __shfl_xor(sm, 8);
        const float inv = 1.f / sm;
        e0 *= inv;
        e1 *= inv;
        p[jsub][0][r] = e0;
        p[jsub][1][r] = e1;
        rsum0 += e0;
        rsum1 += e1;
        if (LAST) {  // mean over h (adjacent li lanes, ih=i*4+h)
          float s0 = e0 + __shfl_xor(e0, 1);
          s0 += __shfl_xor(s0, 2);
          float s1 = e1 + __shfl_xor(e1, 1);
          s1 += __shfl_xor(s1, 2);
          if ((li & 3) == 0) {
            const long jg = jc + jsub * 16 + kg * 4 + r;
            attn_out[((long)b * 8 + (li >> 2)) * 4096 + jg] = s0 * 0.25f;
            attn_out[((long)b * 8 + 4 + (li >> 2)) * 4096 + jg] = s1 * 0.25f;
          }
        }
      }
    }
    // ---- P -> wave-private LDS (bf16, swizzled), then PV ----
    asm volatile("s_waitcnt lgkmcnt(0)" ::: "memory");  // prev pa reads done
#pragma unroll
    for (int g = 0; g < 2; ++g) {
      const int ih = g * 16 + li;
      char* prow = (char*)Pw + ih * 64;
      const int swz = ((ih >> 2) & 3) << 4;
#pragma unroll
      for (int jsub = 0; jsub < 2; ++jsub)
#pragma unroll
        for (int rp = 0; rp < 2; ++rp) {
          const unsigned int pk =
              (unsigned)f2bf(p[jsub][g][2 * rp]) |
              ((unsigned)f2bf(p[jsub][g][2 * rp + 1]) << 16);
          const int jb = (jsub * 16 + kg * 4 + 2 * rp) * 2;
          *(unsigned int*)(prow + (jb ^ swz)) = pk;
        }
    }
    asm volatile("s_waitcnt lgkmcnt(0)" ::: "memory");  // P visible to reads
#pragma unroll
    for (int h = 0; h < 4; ++h) {
      const int ihr = (li & 7) * 4 + h;  // A row = i (li); rows 8..15 dup/ignored
      const frag_ab pa = *(const frag_ab*)(
          (const char*)Pw + ihr * 64 + ((kg * 16) ^ (((ihr >> 2) & 3) << 4)));
#pragma unroll
      for (int dt = 0; dt < 4; ++dt) {
        const frag_ab vf = *(const frag_ab*)(
            Vt + ((long)b * 256 + h * 64 + dt * 16 + li) * 4096 + jc + kg * 8);
        pv[h][dt] =
            __builtin_amdgcn_mfma_f32_16x16x32_bf16(pa, vf, pv[h][dt], 0, 0, 0);
        if (FIRST) {
          const unsigned short* vu = (const unsigned short*)&vf;
          float s = 0.f;
#pragma unroll
          for (int e = 0; e < 8; ++e) s += bf2f(vu[e]);
          svl[h * 4 + dt] += s;
        }
      }
    }
  }

  // ---- end-of-kernel block reductions (single barrier) ----
  if (kg < 2) {
#pragma unroll
    for (int h = 0; h < 4; ++h)
#pragma unroll
      for (int dt = 0; dt < 4; ++dt)
#pragma unroll
        for (int r = 0; r < 4; ++r)
          ured[wid][(kg * 4 + r) * 256 + h * 64 + dt * 16 + li] = pv[h][dt][r];
  }
  rsum0 += __shfl_xor(rsum0, 16);
  rsum0 += __shfl_xor(rsum0, 32);
  rsum1 += __shfl_xor(rsum1, 16);
  rsum1 += __shfl_xor(rsum1, 32);
  if (lane < 16) {
    wred[wid][lane] = rsum0;
    wred[wid][16 + lane] = rsum1;
  }
  if (FIRST) {
#pragma unroll
    for (int u = 0; u < 16; ++u) {
      svl[u] += __shfl_xor(svl[u], 16);
      svl[u] += __shfl_xor(svl[u], 32);
    }
    if (lane < 16) {
#pragma unroll
      for (int h = 0; h < 4; ++h)
#pragma unroll
        for (int dt = 0; dt < 4; ++dt)
          svred[wid][h * 64 + dt * 16 + lane] = svl[h * 4 + dt];
    }
  }
  __syncthreads();
  const long pb = (long)blockIdx.x * 64 + b;
#pragma unroll
  for (int o = 0; o < 8; ++o) {
    const int idx = o * 256 + t;
    const int i = idx >> 8, d = idx & 255;
    upart[(pb * 8 + i) * 256 + d] = ured[0][i * 256 + d] + ured[1][i * 256 + d] +
                                    ured[2][i * 256 + d] + ured[3][i * 256 + d];
  }
  if (t < 32)
    rowsum_part[pb * 32 + t] = wred[0][t] + wred[1][t] + wred[2][t] + wred[3][t];
  if (FIRST)
    svpart[pb * 256 + t] = svred[0][t] + svred[1][t] + svred[2][t] + svred[3][t];
}

// ---------------------------------------------------------------------------
// GRU cell fused with next-iteration LN + q projection. One block per b.
template <bool LAST>
__global__ __launch_bounds__(256) void k_gruq(
    const float* __restrict__ upart, const float* __restrict__ svpart,
    const float* __restrict__ rowsum_part, const float* __restrict__ wihT,
    const float* __restrict__ whhT, const float* __restrict__ bih,
    const float* __restrict__ bhh, const float* __restrict__ lnw,
    const float* __restrict__ lnb, const float* __restrict__ wqT,
    float* __restrict__ slots, float* __restrict__ qout,
    float* __restrict__ dout) {
  __shared__ float xl[8 * 256];
  __shared__ float hl[8 * 256];
  __shared__ float rs[32];
  __shared__ float mstat[8], rstat[8];
  const int t = threadIdx.x;
  const int b = blockIdx.x;
  if (t < 32) {
    float s2 = 0.f;
#pragma unroll
    for (int p = 0; p < 16; ++p) s2 += rowsum_part[((long)(p * 64 + b)) * 32 + t];
    rs[t] = 1.f / (s2 + 4096.f * 1e-8f);
  }
  float svs = 0.f;
#pragma unroll
  for (int p = 0; p < 16; ++p) svs += svpart[((long)(p * 64 + b)) * 256 + t];
  __syncthreads();
  const int hcol = t >> 6;
#pragma unroll
  for (int r = 0; r < 8; ++r) {
    float pp = 0.f;
#pragma unroll
    for (int p = 0; p < 16; ++p)
      pp += upart[(((long)(p * 64 + b)) * 8 + r) * 256 + t];
    xl[r * 256 + t] = (pp + 1e-8f * svs) * rs[r * 4 + hcol];
    hl[r * 256 + t] = slots[b * 2048 + r * 256 + t];
  }
  __syncthreads();
  float air[8] = {}, aiz[8] = {}, ain[8] = {};
  float ahr[8] = {}, ahz[8] = {}, ahn[8] = {};
  for (int k = 0; k < 256; k += 4) {
    float wir[4], wiz[4], win_[4], whr[4], whz[4], whn[4];
#pragma unroll
    for (int u = 0; u < 4; ++u) {
      wir[u] = wihT[(k + u) * 768 + t];
      wiz[u] = wihT[(k + u) * 768 + 256 + t];
      win_[u] = wihT[(k + u) * 768 + 512 + t];
      whr[u] = whhT[(k + u) * 768 + t];
      whz[u] = whhT[(k + u) * 768 + 256 + t];
      whn[u] = whhT[(k + u) * 768 + 512 + t];
    }
#pragma unroll
    for (int r = 0; r < 8; ++r) {
      const float4 x4 = *(const float4*)(xl + r * 256 + k);
      const float4 h4 = *(const float4*)(hl + r * 256 + k);
      air[r] += x4.x * wir[0] + x4.y * wir[1] + x4.z * wir[2] + x4.w * wir[3];
      aiz[r] += x4.x * wiz[0] + x4.y * wiz[1] + x4.z * wiz[2] + x4.w * wiz[3];
      ain[r] += x4.x * win_[0] + x4.y * win_[1] + x4.z * win_[2] + x4.w * win_[3];
      ahr[r] += h4.x * whr[0] + h4.y * whr[1] + h4.z * whr[2] + h4.w * whr[3];
      ahz[r] += h4.x * whz[0] + h4.y * whz[1] + h4.z * whz[2] + h4.w * whz[3];
      ahn[r] += h4.x * whn[0] + h4.y * whn[1] + h4.z * whn[2] + h4.w * whn[3];
    }
  }
  const float bir = bih[t], biz = bih[256 + t], bin_ = bih[512 + t];
  const float bhr = bhh[t], bhz = bhh[256 + t], bhn = bhh[512 + t];
  float hn[8];
#pragma unroll
  for (int r = 0; r < 8; ++r) {
    const float rr = 1.f / (1.f + __expf(-(air[r] + bir + ahr[r] + bhr)));
    const float zz = 1.f / (1.f + __expf(-(aiz[r] + biz + ahz[r] + bhz)));
    const float nn2 = tanhf(ain[r] + bin_ + rr * (ahn[r] + bhn));
    hn[r] = (1.f - zz) * nn2 + zz * hl[r * 256 + t];
    slots[b * 2048 + r * 256 + t] = hn[r];
    if (LAST) dout[b * 2048 + r * 256 + t] = hn[r];
  }
  if (LAST) return;
  // ---- fused LN + q for the next iteration ----
  __syncthreads();
#pragma unroll
  for (int r = 0; r < 8; ++r) xl[r * 256 + t] = hn[r];
  __syncthreads();
  if (t < 8) {
    float s = 0.f, ss = 0.f;
    for (int k = 0; k < 256; ++k) {
      const float x = xl[t * 256 + k];
      s += x;
      ss += x * x;
    }
    const float m = s * (1.f / 256.f);
    mstat[t] = m;
    rstat[t] = rsqrtf(ss * (1.f / 256.f) - m * m + 1e-5f);
  }
  __syncthreads();
  const float w = lnw[t], bb = lnb[t];
#pragma unroll
  for (int i = 0; i < 8; ++i)
    xl[i * 256 + t] = (xl[i * 256 + t] - mstat[i]) * rstat[i] * w + bb;
  __syncthreads();
  float acq[8] = {};
  for (int k = 0; k < 256; k += 4) {
    const float w0 = wqT[(k + 0) * 256 + t];
    const float w1 = wqT[(k + 1) * 256 + t];
    const float w2 = wqT[(k + 2) * 256 + t];
    const float w3 = wqT[(k + 3) * 256 + t];
#pragma unroll
    for (int i = 0; i < 8; ++i) {
      const float4 x4 = *(const float4*)(xl + i * 256 + k);
      acq[i] += x4.x * w0 + x4.y * w1 + x4.z * w2 + x4.w * w3;
    }
  }
#pragma unroll
  for (int i = 0; i < 8; ++i) qout[b * 2048 + i * 256 + t] = acq[i];
}

// ---------------------------------------------------------------------------
extern "C" void kernel_launch(void* const* d_in, const int* in_sizes, int n_in,
                              void* d_out, int out_size, void* d_ws,
                              size_t ws_size, hipStream_t stream) {
  const float* xin = (const float*)d_in[0];
  const float* cond = (const float*)d_in[1];
  const float* lnin_w = (const float*)d_in[2];
  const float* lnin_b = (const float*)d_in[3];
  const float* lns_w = (const float*)d_in[4];
  const float* lns_b = (const float*)d_in[5];
  const float* wq = (const float*)d_in[6];
  const float* wk = (const float*)d_in[7];
  const float* wv = (const float*)d_in[8];
  const float* gwih = (const float*)d_in[9];
  const float* gwhh = (const float*)d_in[10];
  const float* gbih = (const float*)d_in[11];
  const float* gbhh = (const float*)d_in[12];
  float* out = (float*)d_out;

  char* ws = (char*)d_ws;
  unsigned short* Kb = (unsigned short*)ws;  ws += 64l * 4096 * 256 * 2;   // 128MB
  unsigned short* Vt = (unsigned short*)ws;  ws += 64l * 256 * 4096 * 2;   // 128MB
  unsigned short* Xh = (unsigned short*)ws;  ws += 262144l * 256 * 2;      // 128MB
  float* upart = (float*)ws;                 ws += 16l * 64 * 8 * 256 * 4; // 8MB
  float* svpart = (float*)ws;                ws += 16l * 64 * 256 * 4;     // 1MB
  float* rowsum_part = (float*)ws;           ws += 16l * 64 * 32 * 4;
  float* qbuf = (float*)ws;                  ws += 512l * 256 * 4;
  float* slots = (float*)ws;                 ws += 512l * 256 * 4;
  float* wihT = (float*)ws;                  ws += 256l * 768 * 4;
  float* whhT = (float*)ws;                  ws += 256l * 768 * 4;
  float* wqT = (float*)ws;                   ws += 256l * 256 * 4;
  unsigned short* Wb = (unsigned short*)ws;  ws += 512l * 256 * 2;
  // total ~397 MB (ws_size ~1 GB per fill counters)

  hipMemcpyAsync(slots, cond, 512 * 256 * 4, hipMemcpyDeviceToDevice, stream);
  k_wcvt<<<128, 256, 0, stream>>>(wk, wv, Wb);
  k_transpose<<<1792, 256, 0, stream>>>(gwih, gwhh, wq, wihT, whhT, wqT);
  k_precvt<<<65536, 256, 0, stream>>>(xin, lnin_w, lnin_b, Xh);
  k_gemm<<<8192, 256, 0, stream>>>(Xh, Wb, Kb, Vt);
  k_q<<<64, 256, 0, stream>>>(slots, lns_w, lns_b, wqT, qbuf);

  // iter 0
  k_att<false, true><<<dim3(16, 64), 256, 0, stream>>>(
      qbuf, Kb, Vt, upart, svpart, rowsum_part, out + 131072);
  k_gruq<false><<<64, 256, 0, stream>>>(upart, svpart, rowsum_part, wihT, whhT,
                                        gbih, gbhh, lns_w, lns_b, wqT, slots,
                                        qbuf, out);
  // iter 1
  k_att<false, false><<<dim3(16, 64), 256, 0, stream>>>(
      qbuf, Kb, Vt, upart, svpart, rowsum_part, out + 131072);
  k_gruq<false><<<64, 256, 0, stream>>>(upart, svpart, rowsum_part, wihT, whhT,
                                        gbih, gbhh, lns_w, lns_b, wqT, slots,
                                        qbuf, out);
  // iter 2
  k_att<true, false><<<dim3(16, 64), 256, 0, stream>>>(
      qbuf, Kb, Vt, upart, svpart, rowsum_part, out + 131072);
  k_gruq<true><<<64, 256, 0, stream>>>(upart, svpart, rowsum_part, wihT, whhT,
                                       gbih, gbhh, lns_w, lns_b, wqT, slots,
                                       qbuf, out);
}